// Round 4
// baseline (905.073 us; speedup 1.0000x reference)
//
#include <hip/hip_runtime.h>

typedef unsigned short u16;
typedef unsigned int u32;
typedef _Float16 f16;

using half8 = __attribute__((ext_vector_type(8))) _Float16;
using f32x4 = __attribute__((ext_vector_type(4))) float;
using f32x16 = __attribute__((ext_vector_type(16))) float;

// ---------------------------------------------------------------------------
// Prep 1: P1 = feats @ W1a (fp32, Qc folded later), P2h = f16(feats @ W1b)
// ---------------------------------------------------------------------------
__global__ __launch_bounds__(512) void prep_p12(const float* __restrict__ img,
                                                const float* __restrict__ gw1,
                                                float* __restrict__ P1,
                                                f16* __restrict__ P2h) {
    const int blk = blockIdx.x;
    const int n = blk >> 3;
    const int c0 = (blk & 7) * 8;
    const int t = threadIdx.x;
    __shared__ float feats[8][68];
    for (int idx = t; idx < 8 * 66; idx += 512) {
        int rr = idx / 66, cc = idx % 66, cell = c0 + rr;
        float v;
        if (cc < 64)       v = img[((size_t)(n * 64 + cc)) * 64 + cell];
        else if (cc == 64) v = (float)(cell >> 3);
        else               v = (float)(cell & 7);
        feats[rr][cc] = v;
    }
    __syncthreads();
    const int g = t;
    float a1[8], a2[8];
#pragma unroll
    for (int r = 0; r < 8; ++r) { a1[r] = 0.f; a2[r] = 0.f; }
    for (int c = 0; c < 66; ++c) {
        float wa = gw1[(size_t)c * 512 + g];
        float wb = gw1[(size_t)(66 + c) * 512 + g];
#pragma unroll
        for (int r = 0; r < 8; ++r) {
            a1[r] += feats[r][c] * wa;
            a2[r] += feats[r][c] * wb;
        }
    }
#pragma unroll
    for (int r = 0; r < 8; ++r) {
        P1[((size_t)(n * 64 + c0 + r)) * 512 + g] = a1[r];
        P2h[((size_t)(n * 64 + c0 + r)) * 512 + g] = (f16)a2[r];
    }
}

// ---------------------------------------------------------------------------
// Prep 2: Qc[n] = ques[n] @ W1c + b1; P1h = f16(P1 + Qc). Also zero Ctx.
// ---------------------------------------------------------------------------
__global__ __launch_bounds__(512) void prep_q2(const float* __restrict__ ques,
                                               const float* __restrict__ gw1,
                                               const float* __restrict__ gb1,
                                               const float* __restrict__ P1,
                                               f16* __restrict__ P1h,
                                               float* __restrict__ Ctx) {
    const int n = blockIdx.x;
    const int t = threadIdx.x;
    __shared__ float q[256];
    if (t < 256) q[t] = ques[(size_t)n * 256 + t];
    __syncthreads();
    float acc = gb1[t];
    for (int e = 0; e < 256; ++e)
        acc += q[e] * gw1[(size_t)(132 + e) * 512 + t];
    const float* src = P1 + (((size_t)(n * 64)) << 9) + t;
    f16* dst = P1h + (((size_t)(n * 64)) << 9) + t;
    for (int r = 0; r < 64; ++r)
        dst[(size_t)r * 512] = (f16)(src[(size_t)r * 512] + acc);
    Ctx[(size_t)n * 512 + t] = 0.f;
}

// ---------------------------------------------------------------------------
// Prep 3: transpose W2/W3/W4 (512x512 fp32 [k][n] -> fp16 [n][k])
// ---------------------------------------------------------------------------
__global__ void transpose_w(const float* __restrict__ W2, const float* __restrict__ W3,
                            const float* __restrict__ W4, f16* __restrict__ T2,
                            f16* __restrict__ T3, f16* __restrict__ T4) {
    const int L = blockIdx.z;
    const float* W = (L == 0) ? W2 : ((L == 1) ? W3 : W4);
    f16* T = (L == 0) ? T2 : ((L == 1) ? T3 : T4);
    __shared__ float tile[32][33];
    const int bx = blockIdx.x * 32;  // n origin
    const int by = blockIdx.y * 32;  // k origin
    const int tx = threadIdx.x, ty = threadIdx.y;
    for (int r = ty; r < 32; r += 8)
        tile[r][tx] = W[(size_t)(by + r) * 512 + bx + tx];
    __syncthreads();
    for (int r = ty; r < 32; r += 8)
        T[(size_t)(bx + r) * 512 + by + tx] = (f16)tile[tx][r];
}

// ---------------------------------------------------------------------------
// FUSED g-MLP layers 2..4 + mean-reduce. 32x32x16 MFMA, 2x4 (MxN) wave split.
// One block = 128 pair-rows of one image; H tile 128x512 f16 = 128 KB LDS,
// XOR-swizzled: halfidx k ^ ((row&7)<<3).
// Round-2 post-mortem: MFMA throughput is ~1 per 8 cyc PER CU (m119), so the
// MFMA floor for this dispatch is ~165 us; we sat at 512 us because the 1x8
// N-split made every wave read ALL 128 A-rows (8x LDS redundancy, 32 KB/ks)
// and af was consumed in the same iteration it was read (no latency hiding).
// This version:
//  - wave tile 64 rows x 128 cols (wm=wv>>2, wn=wv&3): A-LDS traffic halves
//    (2 b128/ks/wave); B duplication across the wm pair is L1-absorbed.
//  - register double-buffer af AND bf with named A/B sets (static indexing,
//    rule #20): prefetch of ks+1 issues before the MFMA cluster of ks ->
//    counted lgkmcnt/vmcnt, latency hides under the 512-cyc/ks MFMA shadow.
//  - s_setprio(1) around the MFMA cluster (T5).
// Fragment layouts (guide m74/m101):
//   A/B: row|col = lane&31, k = (lane>>5)*8 + j
//   C/D: col = lane&31, row = (reg&3) + 8*(reg>>2) + 4*(lane>>5)
// ---------------------------------------------------------------------------
__global__ __launch_bounds__(512, 2) void fused_g234(
    const f16* __restrict__ P1h, const f16* __restrict__ P2h,
    const f16* __restrict__ T2, const f16* __restrict__ T3,
    const f16* __restrict__ T4, const float* __restrict__ gb2,
    const float* __restrict__ gb3, const float* __restrict__ gb4,
    float* __restrict__ Ctx) {
    const int tid = threadIdx.x;
    const int lane = tid & 63;
    const int lane31 = lane & 31;
    const int khalf = lane >> 5;        // 0..1 (k-subgroup of 8 within ks*16)
    const int wv = tid >> 6;            // 0..7
    const int wm = wv >> 2;             // 0..1 row-half (64 rows)
    const int wn = wv & 3;              // 0..3 col-quarter (128 cols)
    const int b = blockIdx.x;
    const int nb = b >> 5;              // image 0..63
    const int i0 = (b & 31) * 2;        // first of the 2 i-indices

    __shared__ alignas(16) f16 H[128 * 512];   // 128 KB

    const f16* P1b = P1h + (((size_t)(nb * 64 + i0)) << 9);
    const f16* P2b = P2h + (((size_t)(nb * 64)) << 9);

    // ---- construct layer-1 output: H = relu(P1h[i] + P2h[j]), swizzled ----
    {
        const int k0 = lane * 8;
#pragma unroll
        for (int u = 0; u < 16; ++u) {
            int r = u * 8 + wv;                     // r&7 == wv
            half8 x = *(const half8*)(P1b + (((size_t)(r >> 6)) << 9) + k0);
            half8 y = *(const half8*)(P2b + (((size_t)(r & 63)) << 9) + k0);
            half8 s = x + y;
            s = __builtin_elementwise_max(s, (half8)(f16)0.f);
            *(half8*)&H[r * 512 + (k0 ^ ((wv & 7) << 3))] = s;
        }
    }
    __syncthreads();

    f32x16 acc[2][4];
#pragma unroll
    for (int mi = 0; mi < 2; ++mi)
#pragma unroll
        for (int ni = 0; ni < 4; ++ni)
#pragma unroll
            for (int r = 0; r < 16; ++r)
                acc[mi][ni][r] = 0.f;

    const int rbase0 = (wm * 64 + lane31) * 512;
    const int rbase1 = (wm * 64 + 32 + lane31) * 512;
    const int kxor = ((khalf << 3) ^ ((lane31 & 7) << 3));   // half-index bits

    auto ldsA = [&](half8& a0, half8& a1, int ks) {
        const int koff = (ks << 4) ^ kxor;
        a0 = *(const half8*)&H[rbase0 + koff];
        a1 = *(const half8*)&H[rbase1 + koff];
    };
    auto ldB = [&](half8 (&bf)[4], const f16* __restrict__ T, int ks) {
        const f16* p = T + (((size_t)(wn * 128 + lane31)) << 9) + ks * 16 + khalf * 8;
#pragma unroll
        for (int ni = 0; ni < 4; ++ni)
            bf[ni] = *(const half8*)(p + ((size_t)ni << 14));  // +32 cols = 32*512
    };
    auto mfma8 = [&](half8& a0, half8& a1, half8 (&bf)[4]) {
        __builtin_amdgcn_s_setprio(1);
#pragma unroll
        for (int ni = 0; ni < 4; ++ni)
            acc[0][ni] = __builtin_amdgcn_mfma_f32_32x32x16_f16(
                a0, bf[ni], acc[0][ni], 0, 0, 0);
#pragma unroll
        for (int ni = 0; ni < 4; ++ni)
            acc[1][ni] = __builtin_amdgcn_mfma_f32_32x32x16_f16(
                a1, bf[ni], acc[1][ni], 0, 0, 0);
        __builtin_amdgcn_s_setprio(0);
    };

    // One 512-K GEMM layer: 32 ks chunks (K=16), software-pipelined depth 1,
    // no barriers inside. Named A/B register sets keep indexing static.
    auto run_layer = [&](const f16* __restrict__ T) {
        half8 a0A, a1A, a0B, a1B, bfA[4], bfB[4];
        ldsA(a0A, a1A, 0);
        ldB(bfA, T, 0);
        for (int ks = 0; ks < 32; ks += 2) {
            ldsA(a0B, a1B, ks + 1);
            ldB(bfB, T, ks + 1);
            mfma8(a0A, a1A, bfA);
            if (ks + 2 < 32) {
                ldsA(a0A, a1A, ks + 2);
                ldB(bfA, T, ks + 2);
            }
            mfma8(a0B, a1B, bfB);
        }
    };

    // relu(acc+bias) -> f16 -> H (swizzled), zero acc. Two barriers.
    // Bank check: lanes 0-31 (khalf=0) and 32-63 (khalf=1) land in disjoint
    // 64-byte windows (swizzle bit5 toggles with khalf) -> 32 banks, 2-way.
    auto writeback = [&](const float* __restrict__ bias) {
        float bb[4];
#pragma unroll
        for (int ni = 0; ni < 4; ++ni)
            bb[ni] = bias[wn * 128 + ni * 32 + lane31];
        __syncthreads();                    // all waves done reading H
#pragma unroll
        for (int mi = 0; mi < 2; ++mi) {
#pragma unroll
            for (int ni = 0; ni < 4; ++ni) {
                const int col = wn * 128 + ni * 32 + lane31;
#pragma unroll
                for (int r = 0; r < 16; ++r) {
                    const int row = wm * 64 + mi * 32 + (r & 3) + 4 * khalf + 8 * (r >> 2);
                    float v = fmaxf(acc[mi][ni][r] + bb[ni], 0.f);
                    H[row * 512 + (col ^ ((row & 7) << 3))] = (f16)v;
                    acc[mi][ni][r] = 0.f;
                }
            }
        }
        __syncthreads();                    // H rewrite complete
    };

    run_layer(T2);
    writeback(gb2);
    run_layer(T3);
    writeback(gb3);
    run_layer(T4);

    // ---- layer-4 epilogue: relu(acc+b4), col-sum over the wave's 64 rows ----
#pragma unroll
    for (int ni = 0; ni < 4; ++ni) {
        const int col = wn * 128 + ni * 32 + lane31;
        float bb = gb4[col];
        float s = 0.f;
#pragma unroll
        for (int mi = 0; mi < 2; ++mi)
#pragma unroll
            for (int r = 0; r < 16; ++r)
                s += fmaxf(acc[mi][ni][r] + bb, 0.f);
        s += __shfl_xor(s, 32, 64);         // combine the two khalf lanes
        if (khalf == 0)
            atomicAdd(&Ctx[(((size_t)nb) << 9) + col], s);
    }
}

// ---------------------------------------------------------------------------
// f-MLP layer: Out[n, cs*64..+64) = relu(In[n,:]*scale @ W + b).
// ---------------------------------------------------------------------------
__global__ __launch_bounds__(512) void fmlp_layer(
    const float* __restrict__ In, const float* __restrict__ Wt,
    const float* __restrict__ bias, float* __restrict__ Out, float scale) {
    const int n = blockIdx.x, cs = blockIdx.y;
    const int t = threadIdx.x;
    const int col = cs * 64 + (t & 63);
    const int seg = t >> 6;
    __shared__ float a[512];
    __shared__ float red[512];
    a[t] = In[(size_t)n * 512 + t] * scale;
    __syncthreads();
    float p = 0.f;
#pragma unroll 8
    for (int i = seg * 64; i < seg * 64 + 64; ++i)
        p += a[i] * Wt[(size_t)i * 512 + col];
    red[t] = p;
    __syncthreads();
    if (t < 64) {
        float v = bias[col];
#pragma unroll
        for (int sg = 0; sg < 8; ++sg) v += red[sg * 64 + t];
        Out[(size_t)n * 512 + cs * 64 + t] = fmaxf(v, 0.f);
    }
}

// ---------------------------------------------------------------------------
// Final logits + log_softmax. grid 64, block 64 (one wave per batch row).
// ---------------------------------------------------------------------------
__global__ __launch_bounds__(64) void fmlp_out(
    const float* __restrict__ A2, const float* __restrict__ fw3,
    const float* __restrict__ fb3, float* __restrict__ out) {
    const int n = blockIdx.x;
    const int lane = threadIdx.x;
    float s0 = 0.f, s1 = 0.f;
    for (int i = lane; i < 512; i += 64) {
        float v = A2[(size_t)n * 512 + i];
        s0 += v * fw3[i * 2];
        s1 += v * fw3[i * 2 + 1];
    }
#pragma unroll
    for (int d = 1; d < 64; d <<= 1) {
        s0 += __shfl_xor(s0, d, 64);
        s1 += __shfl_xor(s1, d, 64);
    }
    if (lane == 0) {
        s0 += fb3[0];
        s1 += fb3[1];
        float m = fmaxf(s0, s1);
        float l = logf(expf(s0 - m) + expf(s1 - m)) + m;
        out[n * 2 + 0] = s0 - l;
        out[n * 2 + 1] = s1 - l;
    }
}

// ---------------------------------------------------------------------------
extern "C" void kernel_launch(void* const* d_in, const int* in_sizes, int n_in,
                              void* d_out, int out_size, void* d_ws, size_t ws_size,
                              hipStream_t stream) {
    const float* img  = (const float*)d_in[0];
    const float* ques = (const float*)d_in[1];
    const float* gw1  = (const float*)d_in[2];
    const float* gb1  = (const float*)d_in[3];
    const float* gw2  = (const float*)d_in[4];
    const float* gb2  = (const float*)d_in[5];
    const float* gw3  = (const float*)d_in[6];
    const float* gb3  = (const float*)d_in[7];
    const float* gw4  = (const float*)d_in[8];
    const float* gb4  = (const float*)d_in[9];
    const float* fw1  = (const float*)d_in[10];
    const float* fb1  = (const float*)d_in[11];
    const float* fw2  = (const float*)d_in[12];
    const float* fb2  = (const float*)d_in[13];
    const float* fw3  = (const float*)d_in[14];
    const float* fb3  = (const float*)d_in[15];

    char* ws = (char*)d_ws;
    size_t off = 0;
    float* P1  = (float*)(ws + off); off += (size_t)4096 * 512 * 4;   // 8 MB fp32 scratch
    f16* P1h = (f16*)(ws + off); off += (size_t)4096 * 512 * 2;       // 4 MB (P1+Qc, f16)
    f16* P2h = (f16*)(ws + off); off += (size_t)4096 * 512 * 2;       // 4 MB
    float* Ctx = (float*)(ws + off); off += (size_t)64 * 512 * 4;
    float* Z1  = (float*)(ws + off); off += (size_t)64 * 512 * 4;
    float* Z2  = (float*)(ws + off); off += (size_t)64 * 512 * 4;
    f16* T2 = (f16*)(ws + off); off += (size_t)512 * 512 * 2;
    f16* T3 = (f16*)(ws + off); off += (size_t)512 * 512 * 2;
    f16* T4 = (f16*)(ws + off); off += (size_t)512 * 512 * 2;

    prep_p12<<<512, 512, 0, stream>>>(img, gw1, P1, P2h);
    prep_q2<<<64, 512, 0, stream>>>(ques, gw1, gb1, P1, P1h, Ctx);
    transpose_w<<<dim3(16, 16, 3), dim3(32, 8), 0, stream>>>(gw2, gw3, gw4, T2, T3, T4);

    // one fused dispatch replaces the 12 chunked GEMMs (zero HBM intermediates)
    fused_g234<<<2048, 512, 0, stream>>>(P1h, P2h, T2, T3, T4, gb2, gb3, gb4, Ctx);

    fmlp_layer<<<dim3(64, 8), 512, 0, stream>>>(Ctx, fw1, fb1, Z1, 1.0f / 4096.0f);
    fmlp_layer<<<dim3(64, 8), 512, 0, stream>>>(Z1, fw2, fb2, Z2, 1.0f);
    fmlp_out<<<64, 64, 0, stream>>>(Z2, fw3, fb3, (float*)d_out);
}

// Round 5
// 720.156 us; speedup vs baseline: 1.2568x; 1.2568x over previous
//
#include <hip/hip_runtime.h>

typedef unsigned short u16;
typedef unsigned int u32;
typedef _Float16 f16;

using half8 = __attribute__((ext_vector_type(8))) _Float16;
using f32x4 = __attribute__((ext_vector_type(4))) float;
using f32x16 = __attribute__((ext_vector_type(16))) float;

// ---------------------------------------------------------------------------
// Prep 1: P1 = feats @ W1a (fp32, Qc folded later), P2h = f16(feats @ W1b)
// ---------------------------------------------------------------------------
__global__ __launch_bounds__(512) void prep_p12(const float* __restrict__ img,
                                                const float* __restrict__ gw1,
                                                float* __restrict__ P1,
                                                f16* __restrict__ P2h) {
    const int blk = blockIdx.x;
    const int n = blk >> 3;
    const int c0 = (blk & 7) * 8;
    const int t = threadIdx.x;
    __shared__ float feats[8][68];
    for (int idx = t; idx < 8 * 66; idx += 512) {
        int rr = idx / 66, cc = idx % 66, cell = c0 + rr;
        float v;
        if (cc < 64)       v = img[((size_t)(n * 64 + cc)) * 64 + cell];
        else if (cc == 64) v = (float)(cell >> 3);
        else               v = (float)(cell & 7);
        feats[rr][cc] = v;
    }
    __syncthreads();
    const int g = t;
    float a1[8], a2[8];
#pragma unroll
    for (int r = 0; r < 8; ++r) { a1[r] = 0.f; a2[r] = 0.f; }
    for (int c = 0; c < 66; ++c) {
        float wa = gw1[(size_t)c * 512 + g];
        float wb = gw1[(size_t)(66 + c) * 512 + g];
#pragma unroll
        for (int r = 0; r < 8; ++r) {
            a1[r] += feats[r][c] * wa;
            a2[r] += feats[r][c] * wb;
        }
    }
#pragma unroll
    for (int r = 0; r < 8; ++r) {
        P1[((size_t)(n * 64 + c0 + r)) * 512 + g] = a1[r];
        P2h[((size_t)(n * 64 + c0 + r)) * 512 + g] = (f16)a2[r];
    }
}

// ---------------------------------------------------------------------------
// Prep 2: Qc[n] = ques[n] @ W1c + b1; P1h = f16(P1 + Qc). Also zero Ctx.
// ---------------------------------------------------------------------------
__global__ __launch_bounds__(512) void prep_q2(const float* __restrict__ ques,
                                               const float* __restrict__ gw1,
                                               const float* __restrict__ gb1,
                                               const float* __restrict__ P1,
                                               f16* __restrict__ P1h,
                                               float* __restrict__ Ctx) {
    const int n = blockIdx.x;
    const int t = threadIdx.x;
    __shared__ float q[256];
    if (t < 256) q[t] = ques[(size_t)n * 256 + t];
    __syncthreads();
    float acc = gb1[t];
    for (int e = 0; e < 256; ++e)
        acc += q[e] * gw1[(size_t)(132 + e) * 512 + t];
    const float* src = P1 + (((size_t)(n * 64)) << 9) + t;
    f16* dst = P1h + (((size_t)(n * 64)) << 9) + t;
    for (int r = 0; r < 64; ++r)
        dst[(size_t)r * 512] = (f16)(src[(size_t)r * 512] + acc);
    Ctx[(size_t)n * 512 + t] = 0.f;
}

// ---------------------------------------------------------------------------
// Prep 3: reorder W2/W3/W4 (512x512 fp32 [k][n]) into K-chunk-major f16:
//   T'[ks][khalf][col][8]  (ks = k>>4, khalf = (k>>3)&1, j = k&7)
//   halfidx = ks*8192 + khalf*4096 + col*8 + j      (16 KB per ks chunk)
// This makes the fused kernel's per-wave B-fragment load CONTIGUOUS:
// lanes 0-31 read 512 B straight (8 cache lines vs 32-line gather before).
// ---------------------------------------------------------------------------
__global__ void transpose_w(const float* __restrict__ W2, const float* __restrict__ W3,
                            const float* __restrict__ W4, f16* __restrict__ T2,
                            f16* __restrict__ T3, f16* __restrict__ T4) {
    const int L = blockIdx.z;
    const float* W = (L == 0) ? W2 : ((L == 1) ? W3 : W4);
    f16* T = (L == 0) ? T2 : ((L == 1) ? T3 : T4);
    __shared__ float tile[32][33];
    const int bx = blockIdx.x * 32;  // n origin
    const int by = blockIdx.y * 32;  // k origin
    const int tx = threadIdx.x, ty = threadIdx.y;
    for (int r = ty; r < 32; r += 8)
        tile[r][tx] = W[(size_t)(by + r) * 512 + bx + tx];
    __syncthreads();
    for (int r = ty; r < 32; r += 8) {
        const int n = bx + r, k = by + tx;
        T[(size_t)(k >> 4) * 8192 + ((k >> 3) & 1) * 4096 + n * 8 + (k & 7)] =
            (f16)tile[tx][r];
    }
}

// ---------------------------------------------------------------------------
// FUSED g-MLP layers 2..4 + mean-reduce. 32x32x16 MFMA, 1x8 (N-only) split.
// One block = 128 pair-rows of one image; H tile 128x512 f16 = 128 KB LDS,
// XOR-swizzled: halfidx k ^ ((row&7)<<3).
// Round-4 post-mortem: the regression (and round-2's 512us plateau) was the
// B GATHER: ldB read 16B/lane at 1KB stride = 32 cache lines per load. Per
// CU per ks: round2 = 512 line-transactions (L1 saturated), round4 = 1024
// (2x oversubscribed -> MfmaUtil 20%). Fix: T' K-chunk-major layout (see
// transpose_w) makes each B-load two contiguous 512B segments (8 lines).
// B goes straight to registers (no LDS staging), depth-1 named dbuf; ~512
// cyc between a wave's ks iterations hides L2 latency. 1x8 split keeps B
// per-wave-disjoint (block B traffic 512 KB/layer, L2 ~12-15 TB/s agg).
// A-reads keep the 4-way bank conflict (floor for b128 row-gather; 1.58x).
// Fragment layouts (guide m74/m101):
//   A/B: row|col = lane&31, k = (lane>>5)*8 + j
//   C/D: col = lane&31, row = (reg&3) + 8*(reg>>2) + 4*(lane>>5)
// ---------------------------------------------------------------------------
__global__ __launch_bounds__(512, 2) void fused_g234(
    const f16* __restrict__ P1h, const f16* __restrict__ P2h,
    const f16* __restrict__ T2, const f16* __restrict__ T3,
    const f16* __restrict__ T4, const float* __restrict__ gb2,
    const float* __restrict__ gb3, const float* __restrict__ gb4,
    float* __restrict__ Ctx) {
    const int tid = threadIdx.x;
    const int lane = tid & 63;
    const int lane31 = lane & 31;
    const int khalf = lane >> 5;        // 0..1 (k-subgroup of 8 within ks*16)
    const int wv = tid >> 6;            // 0..7 (column group of 64)
    const int b = blockIdx.x;
    const int nb = b >> 5;              // image 0..63
    const int i0 = (b & 31) * 2;        // first of the 2 i-indices

    __shared__ alignas(16) f16 H[128 * 512];   // 128 KB

    const f16* P1b = P1h + (((size_t)(nb * 64 + i0)) << 9);
    const f16* P2b = P2h + (((size_t)(nb * 64)) << 9);

    // ---- construct layer-1 output: H = relu(P1h[i] + P2h[j]), swizzled ----
    {
        const int k0 = lane * 8;
#pragma unroll
        for (int u = 0; u < 16; ++u) {
            int r = u * 8 + wv;                     // r&7 == wv
            half8 x = *(const half8*)(P1b + (((size_t)(r >> 6)) << 9) + k0);
            half8 y = *(const half8*)(P2b + (((size_t)(r & 63)) << 9) + k0);
            half8 s = x + y;
            s = __builtin_elementwise_max(s, (half8)(f16)0.f);
            *(half8*)&H[r * 512 + (k0 ^ ((wv & 7) << 3))] = s;
        }
    }
    __syncthreads();

    f32x16 acc[4][2];
#pragma unroll
    for (int mi = 0; mi < 4; ++mi)
#pragma unroll
        for (int ni = 0; ni < 2; ++ni)
#pragma unroll
            for (int r = 0; r < 16; ++r)
                acc[mi][ni][r] = 0.f;

    const int swz = (lane31 & 7) << 3;  // A-row&7 == lane31&7 for all mi

    auto ldsA = [&](half8 (&a)[4], int ks) {
        const int koff = ((ks << 4) | (khalf << 3)) ^ swz;
#pragma unroll
        for (int mi = 0; mi < 4; ++mi)
            a[mi] = *(const half8*)&H[(mi * 32 + lane31) * 512 + koff];
    };
    // B fragment from T' chunk: contiguous 512B per half-wave (coalesced).
    auto ldB = [&](half8 (&bf)[2], const f16* __restrict__ T, int ks) {
        const f16* p = T + ks * 8192 + khalf * 4096 + (wv * 64 + lane31) * 8;
#pragma unroll
        for (int ni = 0; ni < 2; ++ni)
            bf[ni] = *(const half8*)(p + ni * 256);   // +32 cols
    };
    auto mfma8 = [&](half8 (&a)[4], half8 (&bf)[2]) {
        __builtin_amdgcn_s_setprio(1);
#pragma unroll
        for (int mi = 0; mi < 4; ++mi)
#pragma unroll
            for (int ni = 0; ni < 2; ++ni)
                acc[mi][ni] = __builtin_amdgcn_mfma_f32_32x32x16_f16(
                    a[mi], bf[ni], acc[mi][ni], 0, 0, 0);
        __builtin_amdgcn_s_setprio(0);
    };

    // One 512-K GEMM layer: 32 ks chunks (K=16), software-pipelined depth 1,
    // no barriers inside. Named A/B register sets keep indexing static.
    auto run_layer = [&](const f16* __restrict__ T) {
        half8 aA[4], aB[4], bA[2], bB[2];
        ldsA(aA, 0);
        ldB(bA, T, 0);
        for (int ks = 0; ks < 32; ks += 2) {
            ldsA(aB, ks + 1);
            ldB(bB, T, ks + 1);
            mfma8(aA, bA);
            if (ks + 2 < 32) {
                ldsA(aA, ks + 2);
                ldB(bA, T, ks + 2);
            }
            mfma8(aB, bB);
        }
    };

    // relu(acc+bias) -> f16 -> H (swizzled), zero acc. Two barriers.
    auto writeback = [&](const float* __restrict__ bias) {
        float bb[2];
#pragma unroll
        for (int ni = 0; ni < 2; ++ni)
            bb[ni] = bias[wv * 64 + ni * 32 + lane31];
        __syncthreads();                    // all waves done reading H
#pragma unroll
        for (int mi = 0; mi < 4; ++mi) {
#pragma unroll
            for (int ni = 0; ni < 2; ++ni) {
                const int col = wv * 64 + ni * 32 + lane31;
#pragma unroll
                for (int r = 0; r < 16; ++r) {
                    const int row = mi * 32 + (r & 3) + 4 * khalf + 8 * (r >> 2);
                    float v = fmaxf(acc[mi][ni][r] + bb[ni], 0.f);
                    H[row * 512 + (col ^ ((row & 7) << 3))] = (f16)v;
                    acc[mi][ni][r] = 0.f;
                }
            }
        }
        __syncthreads();                    // H rewrite complete
    };

    run_layer(T2);
    writeback(gb2);
    run_layer(T3);
    writeback(gb3);
    run_layer(T4);

    // ---- layer-4 epilogue: relu(acc+b4), col-sum over the block's 128 rows ----
#pragma unroll
    for (int ni = 0; ni < 2; ++ni) {
        const int col = wv * 64 + ni * 32 + lane31;
        float bb = gb4[col];
        float s = 0.f;
#pragma unroll
        for (int mi = 0; mi < 4; ++mi)
#pragma unroll
            for (int r = 0; r < 16; ++r)
                s += fmaxf(acc[mi][ni][r] + bb, 0.f);
        s += __shfl_xor(s, 32, 64);         // combine the two khalf lanes
        if (khalf == 0)
            atomicAdd(&Ctx[(((size_t)nb) << 9) + col], s);
    }
}

// ---------------------------------------------------------------------------
// f-MLP layer: Out[n, cs*64..+64) = relu(In[n,:]*scale @ W + b).
// ---------------------------------------------------------------------------
__global__ __launch_bounds__(512) void fmlp_layer(
    const float* __restrict__ In, const float* __restrict__ Wt,
    const float* __restrict__ bias, float* __restrict__ Out, float scale) {
    const int n = blockIdx.x, cs = blockIdx.y;
    const int t = threadIdx.x;
    const int col = cs * 64 + (t & 63);
    const int seg = t >> 6;
    __shared__ float a[512];
    __shared__ float red[512];
    a[t] = In[(size_t)n * 512 + t] * scale;
    __syncthreads();
    float p = 0.f;
#pragma unroll 8
    for (int i = seg * 64; i < seg * 64 + 64; ++i)
        p += a[i] * Wt[(size_t)i * 512 + col];
    red[t] = p;
    __syncthreads();
    if (t < 64) {
        float v = bias[col];
#pragma unroll
        for (int sg = 0; sg < 8; ++sg) v += red[sg * 64 + t];
        Out[(size_t)n * 512 + cs * 64 + t] = fmaxf(v, 0.f);
    }
}

// ---------------------------------------------------------------------------
// Final logits + log_softmax. grid 64, block 64 (one wave per batch row).
// ---------------------------------------------------------------------------
__global__ __launch_bounds__(64) void fmlp_out(
    const float* __restrict__ A2, const float* __restrict__ fw3,
    const float* __restrict__ fb3, float* __restrict__ out) {
    const int n = blockIdx.x;
    const int lane = threadIdx.x;
    float s0 = 0.f, s1 = 0.f;
    for (int i = lane; i < 512; i += 64) {
        float v = A2[(size_t)n * 512 + i];
        s0 += v * fw3[i * 2];
        s1 += v * fw3[i * 2 + 1];
    }
#pragma unroll
    for (int d = 1; d < 64; d <<= 1) {
        s0 += __shfl_xor(s0, d, 64);
        s1 += __shfl_xor(s1, d, 64);
    }
    if (lane == 0) {
        s0 += fb3[0];
        s1 += fb3[1];
        float m = fmaxf(s0, s1);
        float l = logf(expf(s0 - m) + expf(s1 - m)) + m;
        out[n * 2 + 0] = s0 - l;
        out[n * 2 + 1] = s1 - l;
    }
}

// ---------------------------------------------------------------------------
extern "C" void kernel_launch(void* const* d_in, const int* in_sizes, int n_in,
                              void* d_out, int out_size, void* d_ws, size_t ws_size,
                              hipStream_t stream) {
    const float* img  = (const float*)d_in[0];
    const float* ques = (const float*)d_in[1];
    const float* gw1  = (const float*)d_in[2];
    const float* gb1  = (const float*)d_in[3];
    const float* gw2  = (const float*)d_in[4];
    const float* gb2  = (const float*)d_in[5];
    const float* gw3  = (const float*)d_in[6];
    const float* gb3  = (const float*)d_in[7];
    const float* gw4  = (const float*)d_in[8];
    const float* gb4  = (const float*)d_in[9];
    const float* fw1  = (const float*)d_in[10];
    const float* fb1  = (const float*)d_in[11];
    const float* fw2  = (const float*)d_in[12];
    const float* fb2  = (const float*)d_in[13];
    const float* fw3  = (const float*)d_in[14];
    const float* fb3  = (const float*)d_in[15];

    char* ws = (char*)d_ws;
    size_t off = 0;
    float* P1  = (float*)(ws + off); off += (size_t)4096 * 512 * 4;   // 8 MB fp32 scratch
    f16* P1h = (f16*)(ws + off); off += (size_t)4096 * 512 * 2;       // 4 MB (P1+Qc, f16)
    f16* P2h = (f16*)(ws + off); off += (size_t)4096 * 512 * 2;       // 4 MB
    float* Ctx = (float*)(ws + off); off += (size_t)64 * 512 * 4;
    float* Z1  = (float*)(ws + off); off += (size_t)64 * 512 * 4;
    float* Z2  = (float*)(ws + off); off += (size_t)64 * 512 * 4;
    f16* T2 = (f16*)(ws + off); off += (size_t)512 * 512 * 2;
    f16* T3 = (f16*)(ws + off); off += (size_t)512 * 512 * 2;
    f16* T4 = (f16*)(ws + off); off += (size_t)512 * 512 * 2;

    prep_p12<<<512, 512, 0, stream>>>(img, gw1, P1, P2h);
    prep_q2<<<64, 512, 0, stream>>>(ques, gw1, gb1, P1, P1h, Ctx);
    transpose_w<<<dim3(16, 16, 3), dim3(32, 8), 0, stream>>>(gw2, gw3, gw4, T2, T3, T4);

    // one fused dispatch replaces the 12 chunked GEMMs (zero HBM intermediates)
    fused_g234<<<2048, 512, 0, stream>>>(P1h, P2h, T2, T3, T4, gb2, gb3, gb4, Ctx);

    fmlp_layer<<<dim3(64, 8), 512, 0, stream>>>(Ctx, fw1, fb1, Z1, 1.0f / 4096.0f);
    fmlp_layer<<<dim3(64, 8), 512, 0, stream>>>(Z1, fw2, fb2, Z2, 1.0f);
    fmlp_out<<<64, 64, 0, stream>>>(Z2, fw3, fb3, (float*)d_out);
}

// Round 6
// 476.016 us; speedup vs baseline: 1.9013x; 1.5129x over previous
//
#include <hip/hip_runtime.h>

typedef unsigned short u16;
typedef unsigned int u32;
typedef _Float16 f16;

using half8 = __attribute__((ext_vector_type(8))) _Float16;
using f32x4 = __attribute__((ext_vector_type(4))) float;
using f32x16 = __attribute__((ext_vector_type(16))) float;

// ---------------------------------------------------------------------------
// Prep 1: P1 = feats @ W1a (fp32, Qc folded later), P2h = f16(feats @ W1b)
// ---------------------------------------------------------------------------
__global__ __launch_bounds__(512) void prep_p12(const float* __restrict__ img,
                                                const float* __restrict__ gw1,
                                                float* __restrict__ P1,
                                                f16* __restrict__ P2h) {
    const int blk = blockIdx.x;
    const int n = blk >> 3;
    const int c0 = (blk & 7) * 8;
    const int t = threadIdx.x;
    __shared__ float feats[8][68];
    for (int idx = t; idx < 8 * 66; idx += 512) {
        int rr = idx / 66, cc = idx % 66, cell = c0 + rr;
        float v;
        if (cc < 64)       v = img[((size_t)(n * 64 + cc)) * 64 + cell];
        else if (cc == 64) v = (float)(cell >> 3);
        else               v = (float)(cell & 7);
        feats[rr][cc] = v;
    }
    __syncthreads();
    const int g = t;
    float a1[8], a2[8];
#pragma unroll
    for (int r = 0; r < 8; ++r) { a1[r] = 0.f; a2[r] = 0.f; }
    for (int c = 0; c < 66; ++c) {
        float wa = gw1[(size_t)c * 512 + g];
        float wb = gw1[(size_t)(66 + c) * 512 + g];
#pragma unroll
        for (int r = 0; r < 8; ++r) {
            a1[r] += feats[r][c] * wa;
            a2[r] += feats[r][c] * wb;
        }
    }
#pragma unroll
    for (int r = 0; r < 8; ++r) {
        P1[((size_t)(n * 64 + c0 + r)) * 512 + g] = a1[r];
        P2h[((size_t)(n * 64 + c0 + r)) * 512 + g] = (f16)a2[r];
    }
}

// ---------------------------------------------------------------------------
// Prep 2: Qc[n] = ques[n] @ W1c + b1; P1h = f16(P1 + Qc). Also zero Ctx.
// ---------------------------------------------------------------------------
__global__ __launch_bounds__(512) void prep_q2(const float* __restrict__ ques,
                                               const float* __restrict__ gw1,
                                               const float* __restrict__ gb1,
                                               const float* __restrict__ P1,
                                               f16* __restrict__ P1h,
                                               float* __restrict__ Ctx) {
    const int n = blockIdx.x;
    const int t = threadIdx.x;
    __shared__ float q[256];
    if (t < 256) q[t] = ques[(size_t)n * 256 + t];
    __syncthreads();
    float acc = gb1[t];
    for (int e = 0; e < 256; ++e)
        acc += q[e] * gw1[(size_t)(132 + e) * 512 + t];
    const float* src = P1 + (((size_t)(n * 64)) << 9) + t;
    f16* dst = P1h + (((size_t)(n * 64)) << 9) + t;
    for (int r = 0; r < 64; ++r)
        dst[(size_t)r * 512] = (f16)(src[(size_t)r * 512] + acc);
    Ctx[(size_t)n * 512 + t] = 0.f;
}

// ---------------------------------------------------------------------------
// Prep 3: reorder W2/W3/W4 (512x512 fp32 [k][n]) into K-chunk-major f16:
//   T'[ks][khalf][col][8]  (ks = k>>4, khalf = (k>>3)&1, j = k&7)
//   halfidx = ks*8192 + khalf*4096 + col*8 + j      (16 KB per ks chunk)
// This makes the fused kernel's per-wave B-fragment load CONTIGUOUS:
// lanes 0-31 read 512 B straight (8 cache lines vs 32-line gather before).
// ---------------------------------------------------------------------------
__global__ void transpose_w(const float* __restrict__ W2, const float* __restrict__ W3,
                            const float* __restrict__ W4, f16* __restrict__ T2,
                            f16* __restrict__ T3, f16* __restrict__ T4) {
    const int L = blockIdx.z;
    const float* W = (L == 0) ? W2 : ((L == 1) ? W3 : W4);
    f16* T = (L == 0) ? T2 : ((L == 1) ? T3 : T4);
    __shared__ float tile[32][33];
    const int bx = blockIdx.x * 32;  // n origin
    const int by = blockIdx.y * 32;  // k origin
    const int tx = threadIdx.x, ty = threadIdx.y;
    for (int r = ty; r < 32; r += 8)
        tile[r][tx] = W[(size_t)(by + r) * 512 + bx + tx];
    __syncthreads();
    for (int r = ty; r < 32; r += 8) {
        const int n = bx + r, k = by + tx;
        T[(size_t)(k >> 4) * 8192 + ((k >> 3) & 1) * 4096 + n * 8 + (k & 7)] =
            (f16)tile[tx][r];
    }
}

// ---------------------------------------------------------------------------
// FUSED g-MLP layers 2..4 + mean-reduce. 32x32x16 MFMA, 1x8 (N-only) split.
// One block = 128 pair-rows of one image; H tile 128x512 f16 = 128 KB LDS,
// XOR-swizzled: halfidx k ^ ((row&7)<<3).
// Round-5 post-mortem: the full A+B register double-buffer (48 operand
// VGPRs + 128 AGPR acc) spilled again -> WRITE_SIZE 692 MB of scratch,
// kernel ran at spill speed (644 us). This version keeps round-5's
// coalesced T' B-load but reverts to the round-2-proven register shape:
// B prefetched depth-1 ONLY (bfn[2] = 8 regs), A loaded from LDS
// in-iteration (transient 16 regs), #pragma unroll 2 to bound live ranges.
// Per-CU per-ks budget: MFMA 512 cyc, LDS A-reads ~380-500 cyc (4-way),
// B from L2 ~32 B/cyc -> MFMA/LDS co-saturate, no spill.
// Fragment layouts (guide m74/m101):
//   A/B: row|col = lane&31, k = (lane>>5)*8 + j
//   C/D: col = lane&31, row = (reg&3) + 8*(reg>>2) + 4*(lane>>5)
// ---------------------------------------------------------------------------
__global__ __launch_bounds__(512, 2) void fused_g234(
    const f16* __restrict__ P1h, const f16* __restrict__ P2h,
    const f16* __restrict__ T2, const f16* __restrict__ T3,
    const f16* __restrict__ T4, const float* __restrict__ gb2,
    const float* __restrict__ gb3, const float* __restrict__ gb4,
    float* __restrict__ Ctx) {
    const int tid = threadIdx.x;
    const int lane = tid & 63;
    const int lane31 = lane & 31;
    const int khalf = lane >> 5;        // 0..1 (k-subgroup of 8 within ks*16)
    const int wv = tid >> 6;            // 0..7 (column group of 64)
    const int b = blockIdx.x;
    const int nb = b >> 5;              // image 0..63
    const int i0 = (b & 31) * 2;        // first of the 2 i-indices

    __shared__ alignas(16) f16 H[128 * 512];   // 128 KB

    const f16* P1b = P1h + (((size_t)(nb * 64 + i0)) << 9);
    const f16* P2b = P2h + (((size_t)(nb * 64)) << 9);

    // ---- construct layer-1 output: H = relu(P1h[i] + P2h[j]), swizzled ----
    {
        const int k0 = lane * 8;
#pragma unroll
        for (int u = 0; u < 16; ++u) {
            int r = u * 8 + wv;                     // r&7 == wv
            half8 x = *(const half8*)(P1b + (((size_t)(r >> 6)) << 9) + k0);
            half8 y = *(const half8*)(P2b + (((size_t)(r & 63)) << 9) + k0);
            half8 s = x + y;
            s = __builtin_elementwise_max(s, (half8)(f16)0.f);
            *(half8*)&H[r * 512 + (k0 ^ ((wv & 7) << 3))] = s;
        }
    }
    __syncthreads();

    f32x16 acc[4][2];
#pragma unroll
    for (int mi = 0; mi < 4; ++mi)
#pragma unroll
        for (int ni = 0; ni < 2; ++ni)
#pragma unroll
            for (int r = 0; r < 16; ++r)
                acc[mi][ni][r] = 0.f;

    const int swz = (lane31 & 7) << 3;  // A-row&7 == lane31&7 for all mi

    auto ldsA = [&](half8 (&a)[4], int ks) {
        const int koff = ((ks << 4) | (khalf << 3)) ^ swz;
#pragma unroll
        for (int mi = 0; mi < 4; ++mi)
            a[mi] = *(const half8*)&H[(mi * 32 + lane31) * 512 + koff];
    };
    // B fragment from T' chunk: contiguous 512B per half-wave (coalesced).
    auto ldB = [&](half8 (&bf)[2], const f16* __restrict__ T, int ks) {
        const f16* p = T + ks * 8192 + khalf * 4096 + (wv * 64 + lane31) * 8;
#pragma unroll
        for (int ni = 0; ni < 2; ++ni)
            bf[ni] = *(const half8*)(p + ni * 256);   // +32 cols
    };
    auto mfma8 = [&](half8 (&a)[4], half8 (&bf)[2]) {
        __builtin_amdgcn_s_setprio(1);
#pragma unroll
        for (int mi = 0; mi < 4; ++mi)
#pragma unroll
            for (int ni = 0; ni < 2; ++ni)
                acc[mi][ni] = __builtin_amdgcn_mfma_f32_32x32x16_f16(
                    a[mi], bf[ni], acc[mi][ni], 0, 0, 0);
        __builtin_amdgcn_s_setprio(0);
    };

    // One 512-K GEMM layer: 32 ks chunks (K=16). B prefetched depth-1 only;
    // A read in-iteration (LDS, hidden by the co-resident wave's MFMAs).
    auto run_layer = [&](const f16* __restrict__ T) {
        half8 bfn[2];
        ldB(bfn, T, 0);
#pragma unroll 2
        for (int ks = 0; ks < 32; ++ks) {
            half8 bf[2] = {bfn[0], bfn[1]};
            if (ks < 31) ldB(bfn, T, ks + 1);
            half8 a[4];
            ldsA(a, ks);
            mfma8(a, bf);
        }
    };

    // relu(acc+bias) -> f16 -> H (swizzled), zero acc. Two barriers.
    auto writeback = [&](const float* __restrict__ bias) {
        float bb[2];
#pragma unroll
        for (int ni = 0; ni < 2; ++ni)
            bb[ni] = bias[wv * 64 + ni * 32 + lane31];
        __syncthreads();                    // all waves done reading H
#pragma unroll
        for (int mi = 0; mi < 4; ++mi) {
#pragma unroll
            for (int ni = 0; ni < 2; ++ni) {
                const int col = wv * 64 + ni * 32 + lane31;
#pragma unroll
                for (int r = 0; r < 16; ++r) {
                    const int row = mi * 32 + (r & 3) + 4 * khalf + 8 * (r >> 2);
                    float v = fmaxf(acc[mi][ni][r] + bb[ni], 0.f);
                    H[row * 512 + (col ^ ((row & 7) << 3))] = (f16)v;
                    acc[mi][ni][r] = 0.f;
                }
            }
        }
        __syncthreads();                    // H rewrite complete
    };

    run_layer(T2);
    writeback(gb2);
    run_layer(T3);
    writeback(gb3);
    run_layer(T4);

    // ---- layer-4 epilogue: relu(acc+b4), col-sum over the block's 128 rows ----
#pragma unroll
    for (int ni = 0; ni < 2; ++ni) {
        const int col = wv * 64 + ni * 32 + lane31;
        float bb = gb4[col];
        float s = 0.f;
#pragma unroll
        for (int mi = 0; mi < 4; ++mi)
#pragma unroll
            for (int r = 0; r < 16; ++r)
                s += fmaxf(acc[mi][ni][r] + bb, 0.f);
        s += __shfl_xor(s, 32, 64);         // combine the two khalf lanes
        if (khalf == 0)
            atomicAdd(&Ctx[(((size_t)nb) << 9) + col], s);
    }
}

// ---------------------------------------------------------------------------
// f-MLP layer: Out[n, cs*64..+64) = relu(In[n,:]*scale @ W + b).
// ---------------------------------------------------------------------------
__global__ __launch_bounds__(512) void fmlp_layer(
    const float* __restrict__ In, const float* __restrict__ Wt,
    const float* __restrict__ bias, float* __restrict__ Out, float scale) {
    const int n = blockIdx.x, cs = blockIdx.y;
    const int t = threadIdx.x;
    const int col = cs * 64 + (t & 63);
    const int seg = t >> 6;
    __shared__ float a[512];
    __shared__ float red[512];
    a[t] = In[(size_t)n * 512 + t] * scale;
    __syncthreads();
    float p = 0.f;
#pragma unroll 8
    for (int i = seg * 64; i < seg * 64 + 64; ++i)
        p += a[i] * Wt[(size_t)i * 512 + col];
    red[t] = p;
    __syncthreads();
    if (t < 64) {
        float v = bias[col];
#pragma unroll
        for (int sg = 0; sg < 8; ++sg) v += red[sg * 64 + t];
        Out[(size_t)n * 512 + cs * 64 + t] = fmaxf(v, 0.f);
    }
}

// ---------------------------------------------------------------------------
// Final logits + log_softmax. grid 64, block 64 (one wave per batch row).
// ---------------------------------------------------------------------------
__global__ __launch_bounds__(64) void fmlp_out(
    const float* __restrict__ A2, const float* __restrict__ fw3,
    const float* __restrict__ fb3, float* __restrict__ out) {
    const int n = blockIdx.x;
    const int lane = threadIdx.x;
    float s0 = 0.f, s1 = 0.f;
    for (int i = lane; i < 512; i += 64) {
        float v = A2[(size_t)n * 512 + i];
        s0 += v * fw3[i * 2];
        s1 += v * fw3[i * 2 + 1];
    }
#pragma unroll
    for (int d = 1; d < 64; d <<= 1) {
        s0 += __shfl_xor(s0, d, 64);
        s1 += __shfl_xor(s1, d, 64);
    }
    if (lane == 0) {
        s0 += fb3[0];
        s1 += fb3[1];
        float m = fmaxf(s0, s1);
        float l = logf(expf(s0 - m) + expf(s1 - m)) + m;
        out[n * 2 + 0] = s0 - l;
        out[n * 2 + 1] = s1 - l;
    }
}

// ---------------------------------------------------------------------------
extern "C" void kernel_launch(void* const* d_in, const int* in_sizes, int n_in,
                              void* d_out, int out_size, void* d_ws, size_t ws_size,
                              hipStream_t stream) {
    const float* img  = (const float*)d_in[0];
    const float* ques = (const float*)d_in[1];
    const float* gw1  = (const float*)d_in[2];
    const float* gb1  = (const float*)d_in[3];
    const float* gw2  = (const float*)d_in[4];
    const float* gb2  = (const float*)d_in[5];
    const float* gw3  = (const float*)d_in[6];
    const float* gb3  = (const float*)d_in[7];
    const float* gw4  = (const float*)d_in[8];
    const float* gb4  = (const float*)d_in[9];
    const float* fw1  = (const float*)d_in[10];
    const float* fb1  = (const float*)d_in[11];
    const float* fw2  = (const float*)d_in[12];
    const float* fb2  = (const float*)d_in[13];
    const float* fw3  = (const float*)d_in[14];
    const float* fb3  = (const float*)d_in[15];

    char* ws = (char*)d_ws;
    size_t off = 0;
    float* P1  = (float*)(ws + off); off += (size_t)4096 * 512 * 4;   // 8 MB fp32 scratch
    f16* P1h = (f16*)(ws + off); off += (size_t)4096 * 512 * 2;       // 4 MB (P1+Qc, f16)
    f16* P2h = (f16*)(ws + off); off += (size_t)4096 * 512 * 2;       // 4 MB
    float* Ctx = (float*)(ws + off); off += (size_t)64 * 512 * 4;
    float* Z1  = (float*)(ws + off); off += (size_t)64 * 512 * 4;
    float* Z2  = (float*)(ws + off); off += (size_t)64 * 512 * 4;
    f16* T2 = (f16*)(ws + off); off += (size_t)512 * 512 * 2;
    f16* T3 = (f16*)(ws + off); off += (size_t)512 * 512 * 2;
    f16* T4 = (f16*)(ws + off); off += (size_t)512 * 512 * 2;

    prep_p12<<<512, 512, 0, stream>>>(img, gw1, P1, P2h);
    prep_q2<<<64, 512, 0, stream>>>(ques, gw1, gb1, P1, P1h, Ctx);
    transpose_w<<<dim3(16, 16, 3), dim3(32, 8), 0, stream>>>(gw2, gw3, gw4, T2, T3, T4);

    // one fused dispatch replaces the 12 chunked GEMMs (zero HBM intermediates)
    fused_g234<<<2048, 512, 0, stream>>>(P1h, P2h, T2, T3, T4, gb2, gb3, gb4, Ctx);

    fmlp_layer<<<dim3(64, 8), 512, 0, stream>>>(Ctx, fw1, fb1, Z1, 1.0f / 4096.0f);
    fmlp_layer<<<dim3(64, 8), 512, 0, stream>>>(Z1, fw2, fb2, Z2, 1.0f);
    fmlp_out<<<64, 64, 0, stream>>>(Z2, fw3, fb3, (float*)d_out);
}